// Round 1
// baseline (431.750 us; speedup 1.0000x reference)
//
#include <hip/hip_runtime.h>
#include <math.h>

#define Hh 128   // hidden
#define Nn 32    // docs
#define Ll 128   // doc_len
#define W1S 384  // 3H
#define DTS 132  // padded LDS row stride (words), multiple of 4 for float4
#define CE 16    // e-chunk for W1a staging

__device__ __forceinline__ float fast_tanh(float x) {
  float ax = fabsf(x);
  float e = __expf(ax + ax);          // v_exp_f32 based; inf for big ax -> t=1
  float t = 1.0f - 2.0f / (e + 1.0f);
  return copysignf(t, x);
}

// ent_agg[n,h] = sum_l mask[n,l] * wei[n,l,h]
__global__ void k_entagg(const float* __restrict__ wei, const int* __restrict__ wmask,
                         float* __restrict__ ent) {
  int n = blockIdx.x, h = threadIdx.x;
  const float* wp = wei + (size_t)n * Ll * Hh + h;
  const int* mp = wmask + n * Ll;
  float acc = 0.f;
  for (int l = 0; l < Ll; ++l) acc = fmaf((float)mp[l], wp[(size_t)l * Hh], acc);
  ent[n * Hh + h] = acc;
}

// Bt[n,r,g] = sum_e W1b[g,e]*doc[n,r,e]*ent[n,e] ; Ct[n,r,g] = sum_e W1c[g,e]*doc[n,r,e]*q[n/8,e]
__global__ void k_btct(const float* __restrict__ doc, const float* __restrict__ q,
                       const float* __restrict__ W1, const float* __restrict__ ent,
                       float* __restrict__ Bt, float* __restrict__ Ct) {
  __shared__ __align__(16) float ub[Hh];
  __shared__ __align__(16) float uc[Hh];
  int blk = blockIdx.x, n = blk >> 7, g = threadIdx.x;
  const float* d = doc + (size_t)blk * Hh;
  float dv = d[g];
  ub[g] = dv * ent[n * Hh + g];
  uc[g] = dv * q[(n >> 3) * Hh + g];   // N/B = 8
  __syncthreads();
  const float4* wb = (const float4*)(W1 + (size_t)g * W1S + Hh);
  const float4* wc = (const float4*)(W1 + (size_t)g * W1S + 2 * Hh);
  const float4* u4 = (const float4*)ub;
  const float4* v4 = (const float4*)uc;
  float ab = 0.f, ac = 0.f;
#pragma unroll
  for (int i = 0; i < Hh / 4; ++i) {
    float4 b = wb[i], u = u4[i];
    ab += b.x * u.x + b.y * u.y + b.z * u.z + b.w * u.w;
    float4 c = wc[i], v = v4[i];
    ac += c.x * v.x + c.y * v.y + c.z * v.z + c.w * v.w;
  }
  size_t o = (size_t)blk * Hh + g;
  Bt[o] = ab;
  Ct[o] = ac;
}

// One block per (n, j). hid[g,k] = tanh( sum_e (W1a[g,e]*dj[e]) * doc[n,k,e] + Bt[n,j,g] + Ct[n,k,g] + b1[g] )
// score[k] = (w2 . hid[:,k] + b2)/sqrt(H); masked softmax over k; out[j,:] = sum_k w_k doc[n,k,:]
__launch_bounds__(256, 2)
__global__ void k_main(const float* __restrict__ doc, const int* __restrict__ dmask,
                       const float* __restrict__ W1, const float* __restrict__ b1,
                       const float* __restrict__ w2, const float* __restrict__ b2,
                       const float* __restrict__ Bt, const float* __restrict__ Ct,
                       float* __restrict__ out) {
  __shared__ __align__(16) float Dt[Hh][DTS];  // Dt[e][k] = doc[n,k,e]   (67.6 KB)
  __shared__ __align__(16) float Ws[CE][DTS];  // Ws[e][g] = W1a[g,e0+e]*dj[e0+e]; reused as reduce buf
  __shared__ __align__(16) float djs[Hh];
  __shared__ __align__(16) float sc[Ll];
  __shared__ float rbuf[8];

  int bid = blockIdx.x;
  int n = bid >> 7, j = bid & 127;
  int tid = threadIdx.x;
  int tg = tid >> 4, tk = tid & 15;
  int g0 = tg * 8, k0 = tk * 8;

  const float* docn = doc + (size_t)n * Ll * Hh;

  // stage doc[n] transposed: global coalesced reads, LDS stride-132 writes (~8-way, one-time)
  for (int i = tid; i < Ll * Hh; i += 256) {
    int e = i & 127, k = i >> 7;
    Dt[e][k] = docn[i];
  }
  if (tid < Hh) djs[tid] = docn[(size_t)j * Hh + tid];
  __syncthreads();

  float acc[8][8];
#pragma unroll
  for (int a = 0; a < 8; ++a)
#pragma unroll
    for (int b = 0; b < 8; ++b) acc[a][b] = 0.f;

  for (int e0 = 0; e0 < Hh; e0 += CE) {
    // stage Ws chunk: W1a[g, e0..e0+CE) transposed, dj folded in
    for (int f4 = tid; f4 < (Hh * CE) / 4; f4 += 256) {
      int g = f4 >> 2, c4 = f4 & 3, e = c4 * 4;
      float4 v = *(const float4*)(W1 + (size_t)g * W1S + e0 + e);
      Ws[e + 0][g] = v.x * djs[e0 + e + 0];
      Ws[e + 1][g] = v.y * djs[e0 + e + 1];
      Ws[e + 2][g] = v.z * djs[e0 + e + 2];
      Ws[e + 3][g] = v.w * djs[e0 + e + 3];
    }
    __syncthreads();
#pragma unroll
    for (int e = 0; e < CE; ++e) {
      float4 a0 = *(const float4*)&Ws[e][g0];
      float4 a1 = *(const float4*)&Ws[e][g0 + 4];
      float4 b0 = *(const float4*)&Dt[e0 + e][k0];
      float4 b1v = *(const float4*)&Dt[e0 + e][k0 + 4];
      float av[8] = {a0.x, a0.y, a0.z, a0.w, a1.x, a1.y, a1.z, a1.w};
      float bv[8] = {b0.x, b0.y, b0.z, b0.w, b1v.x, b1v.y, b1v.z, b1v.w};
#pragma unroll
      for (int gi = 0; gi < 8; ++gi)
#pragma unroll
        for (int ki = 0; ki < 8; ++ki)
          acc[gi][ki] = fmaf(av[gi], bv[ki], acc[gi][ki]);
    }
    __syncthreads();
  }

  // epilogue: bias add + tanh + w2-dot partials
  const float* BtJ = Bt + ((size_t)n * Ll + j) * Hh + g0;
  float base[8], w2r[8];
#pragma unroll
  for (int gi = 0; gi < 8; ++gi) {
    base[gi] = BtJ[gi] + b1[g0 + gi];
    w2r[gi] = w2[g0 + gi];
  }
  const float* CtN = Ct + (size_t)n * Ll * Hh;
  float part[8];
#pragma unroll
  for (int ki = 0; ki < 8; ++ki) {
    const float4* ct4 = (const float4*)(CtN + (size_t)(k0 + ki) * Hh + g0);
    float4 c0 = ct4[0], c1 = ct4[1];
    float cv[8] = {c0.x, c0.y, c0.z, c0.w, c1.x, c1.y, c1.z, c1.w};
    float p = 0.f;
#pragma unroll
    for (int gi = 0; gi < 8; ++gi)
      p = fmaf(fast_tanh(acc[gi][ki] + base[gi] + cv[gi]), w2r[gi], p);
    part[ki] = p;
  }
  __syncthreads();                 // done reading Ws as GEMM operand
  float (*red)[DTS] = Ws;          // reuse as [16][132] reduction buffer
#pragma unroll
  for (int ki = 0; ki < 8; ++ki) red[tg][k0 + ki] = part[ki];
  __syncthreads();

  float b2v = b2[0];
  int dmj = dmask[n * Ll + j];
  const float inv = 0.088388347648318447f;  // 1/sqrt(128)
  if (tid < Ll) {
    int k = tid;
    float s = 0.f;
#pragma unroll
    for (int t = 0; t < 16; ++t) s += red[t][k];
    s = (s + b2v) * inv;
    int mk = dmj * dmask[n * Ll + k];
    sc[k] = mk ? s : -1e9f;
  }
  __syncthreads();
  if (tid < Ll) {
    float m = sc[tid];
#pragma unroll
    for (int off = 32; off; off >>= 1) m = fmaxf(m, __shfl_xor(m, off));
    if ((tid & 63) == 0) rbuf[tid >> 6] = m;
  }
  __syncthreads();
  float mx = fmaxf(rbuf[0], rbuf[1]);
  if (tid < Ll) {
    float e = __expf(sc[tid] - mx);
    sc[tid] = e;
    float s = e;
#pragma unroll
    for (int off = 32; off; off >>= 1) s += __shfl_xor(s, off);
    if ((tid & 63) == 0) rbuf[4 + (tid >> 6)] = s;
  }
  __syncthreads();
  float rden = 1.0f / (rbuf[4] + rbuf[5]);
  if (tid < Ll) {
    int mk = dmj * dmask[n * Ll + tid];
    sc[tid] = mk ? sc[tid] * rden : 0.f;   // softmax * score_mask
  }
  __syncthreads();

  // out[j,h] = sum_k w[k] * Dt[h][k]; split k-range across the two thread halves
  int half = tid >> 7, h = tid & 127;
  const float4* w4 = (const float4*)sc;
  float oacc = 0.f;
  for (int t = 0; t < 16; ++t) {
    int k4 = half * 16 + t;
    float4 d = *(const float4*)&Dt[h][k4 * 4];
    float4 wq = w4[k4];
    oacc += d.x * wq.x + d.y * wq.y + d.z * wq.z + d.w * wq.w;
  }
  red[half][h] = oacc;
  __syncthreads();
  if (tid < Ll)
    out[((size_t)n * Ll + j) * Hh + tid] = red[0][tid] + red[1][tid];
}

extern "C" void kernel_launch(void* const* d_in, const int* in_sizes, int n_in,
                              void* d_out, int out_size, void* d_ws, size_t ws_size,
                              hipStream_t stream) {
  const float* wei   = (const float*)d_in[0];
  const int*   wmask = (const int*)d_in[1];
  const float* doc   = (const float*)d_in[2];
  const int*   dmask = (const int*)d_in[3];
  const float* q     = (const float*)d_in[4];
  const float* W1    = (const float*)d_in[5];
  const float* b1    = (const float*)d_in[6];
  const float* w2    = (const float*)d_in[7];
  const float* b2    = (const float*)d_in[8];
  float* out = (float*)d_out;

  float* ws  = (float*)d_ws;
  float* ent = ws;                                   // N*H
  float* Bt  = ws + Nn * Hh;                         // N*L*H
  float* Ct  = Bt + (size_t)Nn * Ll * Hh;            // N*L*H  (total ~4.2 MB)

  k_entagg<<<Nn, Hh, 0, stream>>>(wei, wmask, ent);
  k_btct<<<Nn * Ll, Hh, 0, stream>>>(doc, q, W1, ent, Bt, Ct);
  k_main<<<Nn * Ll, 256, 0, stream>>>(doc, dmask, W1, b1, w2, b2, Bt, Ct, out);
}

// Round 2
// 136.628 us; speedup vs baseline: 3.1600x; 3.1600x over previous
//
#include <hip/hip_runtime.h>
#include <hip/hip_bf16.h>
#include <math.h>

#define Hh 128   // hidden
#define Nn 32    // docs
#define Ll 128   // doc_len
#define W1S 384  // 3H
#define PAD 136  // bf16 elems per LDS row: 272B stride -> 2-way (free) frag reads

typedef __attribute__((ext_vector_type(8))) short short8;
typedef __attribute__((ext_vector_type(4))) float floatx4;

__device__ __forceinline__ unsigned short f2bf(float x) {
  __hip_bfloat16 h = __float2bfloat16(x);
  return __builtin_bit_cast(unsigned short, h);
}

__device__ __forceinline__ short8 pack8(float4 a, float4 b) {
  short8 r;
  r[0] = (short)f2bf(a.x); r[1] = (short)f2bf(a.y);
  r[2] = (short)f2bf(a.z); r[3] = (short)f2bf(a.w);
  r[4] = (short)f2bf(b.x); r[5] = (short)f2bf(b.y);
  r[6] = (short)f2bf(b.z); r[7] = (short)f2bf(b.w);
  return r;
}

// ent_agg[n,h] = sum_l mask[n,l] * wei[n,l,h]
__global__ void k_entagg(const float* __restrict__ wei, const int* __restrict__ wmask,
                         float* __restrict__ ent) {
  __shared__ float red[2][Hh];
  int n = blockIdx.x, tid = threadIdx.x;
  int e = tid & 127, half = tid >> 7;
  const float* wp = wei + (size_t)n * Ll * Hh + (size_t)half * 64 * Hh + e;
  const int* mp = wmask + n * Ll + half * 64;
  float a = 0.f;
#pragma unroll 8
  for (int l = 0; l < 64; ++l)
    a = fmaf((float)mp[l], wp[(size_t)l * Hh], a);
  red[half][e] = a;
  __syncthreads();
  if (tid < Hh) ent[n * Hh + tid] = red[0][tid] + red[1][tid];
}

// Bt[n,k,g] = sum_e W1b[g,e]*doc[n,k,e]*ent[n,e] ; Ct with W1c and q. MFMA version.
// grid = 64: bid = (n, which). which==0 -> Bt (ent), which==1 -> Ct (q).
__launch_bounds__(256, 2)
__global__ void k_btct(const float* __restrict__ doc, const float* __restrict__ q,
                       const float* __restrict__ W1, const float* __restrict__ ent,
                       float* __restrict__ Bt, float* __restrict__ Ct) {
  __shared__ __align__(16) short Xs[Hh * PAD];  // Xs[k][e] = bf16(doc*m)
  __shared__ __align__(16) short Ws[Hh * PAD];  // Ws[g][e] = bf16(W1x)
  __shared__ __align__(16) float ms[Hh];
  int bid = blockIdx.x;
  int n = bid >> 1, which = bid & 1;
  int tid = threadIdx.x;
  const float* docn = doc + (size_t)n * Ll * Hh;
  const float* mv = which ? (q + (n >> 3) * Hh) : (ent + n * Hh);
  if (tid < Hh) ms[tid] = mv[tid];
  __syncthreads();
  const float* wbase = W1 + Hh + which * Hh;
#pragma unroll
  for (int p = 0; p < 8; ++p) {
    int idx = p * 256 + tid;
    int row = idx >> 4;
    int e8 = (idx & 15) * 8;
    const float4* wp = (const float4*)(wbase + (size_t)row * W1S + e8);
    float4 w0 = wp[0], w1 = wp[1];
    *(short8*)(Ws + row * PAD + e8) = pack8(w0, w1);
    const float4* dp = (const float4*)(docn + (size_t)row * Hh + e8);
    float4 d0 = dp[0], d1 = dp[1];
    const float4* mp4 = (const float4*)(ms + e8);
    float4 m0 = mp4[0], m1 = mp4[1];
    d0.x *= m0.x; d0.y *= m0.y; d0.z *= m0.z; d0.w *= m0.w;
    d1.x *= m1.x; d1.y *= m1.y; d1.z *= m1.z; d1.w *= m1.w;
    *(short8*)(Xs + row * PAD + e8) = pack8(d0, d1);
  }
  __syncthreads();

  int lane = tid & 63, w = tid >> 6;
  int l15 = lane & 15, quad = lane >> 4;
  floatx4 acc[2][8];
#pragma unroll
  for (int mt = 0; mt < 2; ++mt)
#pragma unroll
    for (int nt = 0; nt < 8; ++nt)
      acc[mt][nt] = (floatx4){0.f, 0.f, 0.f, 0.f};
#pragma unroll
  for (int e0 = 0; e0 < Hh; e0 += 32) {
    int eo = e0 + quad * 8;
    short8 af[2], bfr[8];
    af[0] = *(const short8*)(Xs + (w * 32 + l15) * PAD + eo);
    af[1] = *(const short8*)(Xs + (w * 32 + 16 + l15) * PAD + eo);
#pragma unroll
    for (int nt = 0; nt < 8; ++nt)
      bfr[nt] = *(const short8*)(Ws + (nt * 16 + l15) * PAD + eo);
#pragma unroll
    for (int mt = 0; mt < 2; ++mt)
#pragma unroll
      for (int nt = 0; nt < 8; ++nt)
        acc[mt][nt] = __builtin_amdgcn_mfma_f32_16x16x32_bf16(af[mt], bfr[nt], acc[mt][nt], 0, 0, 0);
  }
  float* outp = (which ? Ct : Bt) + (size_t)n * Ll * Hh;
#pragma unroll
  for (int mt = 0; mt < 2; ++mt)
#pragma unroll
    for (int nt = 0; nt < 8; ++nt)
#pragma unroll
      for (int r = 0; r < 4; ++r) {
        int k = w * 32 + mt * 16 + quad * 4 + r;
        outp[(size_t)k * Hh + nt * 16 + l15] = acc[mt][nt][r];
      }
}

// One block per (n,j): C[k,g] = sum_e bf16(doc[k,e]*dj[e]) * bf16(W1a[g,e]) via MFMA,
// epilogue tanh + w2-dot + masked softmax + weighted doc sum.
__launch_bounds__(256, 2)
__global__ void k_main(const float* __restrict__ doc, const int* __restrict__ dmask,
                       const float* __restrict__ W1, const float* __restrict__ b1,
                       const float* __restrict__ w2, const float* __restrict__ b2,
                       const float* __restrict__ Bt, const float* __restrict__ Ct,
                       float* __restrict__ out) {
  __shared__ __align__(16) short As[Hh * PAD];  // As[g][e] = bf16(W1a)
  __shared__ __align__(16) short Bs[Hh * PAD];  // Bs[k][e] = bf16(doc*dj)
  __shared__ __align__(16) float djs[Hh];
  __shared__ __align__(16) float sc[Ll];
  __shared__ float rbuf[8];

  int bid = blockIdx.x;
  int n = bid >> 7, j = bid & 127;
  int tid = threadIdx.x;
  const float* docn = doc + (size_t)n * Ll * Hh;
  size_t orow = ((size_t)n * Ll + j) * Hh;

  // row fully masked -> softmax*mask == 0 -> output row is exactly zero (~50% of blocks)
  if (dmask[n * Ll + j] == 0) {
    if (tid < Hh) out[orow + tid] = 0.f;
    return;
  }

  if (tid < Hh) djs[tid] = docn[(size_t)j * Hh + tid];
  __syncthreads();

#pragma unroll
  for (int p = 0; p < 8; ++p) {
    int idx = p * 256 + tid;
    int row = idx >> 4;
    int e8 = (idx & 15) * 8;
    const float4* wp = (const float4*)(W1 + (size_t)row * W1S + e8);
    float4 w0 = wp[0], w1 = wp[1];
    *(short8*)(As + row * PAD + e8) = pack8(w0, w1);
    const float4* dp = (const float4*)(docn + (size_t)row * Hh + e8);
    float4 d0 = dp[0], d1 = dp[1];
    const float4* jp = (const float4*)(djs + e8);
    float4 j0 = jp[0], j1 = jp[1];
    d0.x *= j0.x; d0.y *= j0.y; d0.z *= j0.z; d0.w *= j0.w;
    d1.x *= j1.x; d1.y *= j1.y; d1.z *= j1.z; d1.w *= j1.w;
    *(short8*)(Bs + row * PAD + e8) = pack8(d0, d1);
  }
  __syncthreads();

  int lane = tid & 63, w = tid >> 6;
  int l15 = lane & 15, quad = lane >> 4;
  floatx4 acc[2][8];
#pragma unroll
  for (int mt = 0; mt < 2; ++mt)
#pragma unroll
    for (int nt = 0; nt < 8; ++nt)
      acc[mt][nt] = (floatx4){0.f, 0.f, 0.f, 0.f};
#pragma unroll
  for (int e0 = 0; e0 < Hh; e0 += 32) {
    int eo = e0 + quad * 8;
    short8 af[2], bfr[8];
    af[0] = *(const short8*)(Bs + (w * 32 + l15) * PAD + eo);
    af[1] = *(const short8*)(Bs + (w * 32 + 16 + l15) * PAD + eo);
#pragma unroll
    for (int nt = 0; nt < 8; ++nt)
      bfr[nt] = *(const short8*)(As + (nt * 16 + l15) * PAD + eo);
#pragma unroll
    for (int mt = 0; mt < 2; ++mt)
#pragma unroll
      for (int nt = 0; nt < 8; ++nt)
        acc[mt][nt] = __builtin_amdgcn_mfma_f32_16x16x32_bf16(af[mt], bfr[nt], acc[mt][nt], 0, 0, 0);
  }

  // epilogue: hid = tanh(acc + Ct[k,g] + Bt[j,g] + b1[g]); score[k] = sum_g hid*w2[g]
  // tanh(x) = 1 - 2/(exp2(x*c2)+1), c2 = 2*log2(e)  (sign-safe)
  const float c2 = 2.885390081777927f;
  float bbc[8], w2r[8];
  const float* btrow = Bt + orow;
#pragma unroll
  for (int nt = 0; nt < 8; ++nt) {
    int g = nt * 16 + l15;
    bbc[nt] = (btrow[g] + b1[g]) * c2;
    w2r[nt] = w2[g];
  }
  const float* ctn = Ct + (size_t)n * Ll * Hh;
#pragma unroll
  for (int mt = 0; mt < 2; ++mt) {
#pragma unroll
    for (int r = 0; r < 4; ++r) {
      int k = w * 32 + mt * 16 + quad * 4 + r;
      const float* ctp = ctn + (size_t)k * Hh + l15;
      float p = 0.f;
#pragma unroll
      for (int nt = 0; nt < 8; ++nt) {
        float s = acc[mt][nt][r] + ctp[nt * 16];
        float a2 = fmaf(s, c2, bbc[nt]);
        float e = exp2f(a2);
        float th = fmaf(-2.f, __builtin_amdgcn_rcpf(e + 1.f), 1.f);
        p = fmaf(th, w2r[nt], p);
      }
      p += __shfl_xor(p, 1);
      p += __shfl_xor(p, 2);
      p += __shfl_xor(p, 4);
      p += __shfl_xor(p, 8);
      if (l15 == 0) sc[k] = p;
    }
  }
  __syncthreads();

  // masked softmax over k
  float b2v = b2[0];
  const float inv = 0.088388347648318447f;  // 1/sqrt(128)
  if (tid < Ll) {
    float s = (sc[tid] + b2v) * inv;
    sc[tid] = dmask[n * Ll + tid] ? s : -1e9f;
  }
  __syncthreads();
  if (tid < Ll) {
    float m = sc[tid];
#pragma unroll
    for (int off = 32; off; off >>= 1) m = fmaxf(m, __shfl_xor(m, off));
    if ((tid & 63) == 0) rbuf[tid >> 6] = m;
  }
  __syncthreads();
  float mx = fmaxf(rbuf[0], rbuf[1]);
  if (tid < Ll) {
    float e = __expf(sc[tid] - mx);
    sc[tid] = e;
    float ssum = e;
#pragma unroll
    for (int off = 32; off; off >>= 1) ssum += __shfl_xor(ssum, off);
    if ((tid & 63) == 0) rbuf[4 + (tid >> 6)] = ssum;
  }
  __syncthreads();
  float rden = 1.f / (rbuf[4] + rbuf[5]);
  if (tid < Ll)
    sc[tid] = dmask[n * Ll + tid] ? sc[tid] * rden : 0.f;
  __syncthreads();

  // out[j,h] = sum_k w[k] * doc[n,k,h]
  float* ored = (float*)As;  // As dead after GEMM; reuse as [2][128] reduce buffer
  int half = tid >> 7, h = tid & 127;
  const float* dbase = docn + (size_t)half * 64 * Hh + h;
  float o = 0.f;
#pragma unroll 8
  for (int kk = 0; kk < 64; ++kk)
    o = fmaf(sc[half * 64 + kk], dbase[(size_t)kk * Hh], o);
  ored[half * Hh + h] = o;
  __syncthreads();
  if (tid < Ll) out[orow + tid] = ored[tid] + ored[Hh + tid];
}

extern "C" void kernel_launch(void* const* d_in, const int* in_sizes, int n_in,
                              void* d_out, int out_size, void* d_ws, size_t ws_size,
                              hipStream_t stream) {
  const float* wei   = (const float*)d_in[0];
  const int*   wmask = (const int*)d_in[1];
  const float* doc   = (const float*)d_in[2];
  const int*   dmask = (const int*)d_in[3];
  const float* q     = (const float*)d_in[4];
  const float* W1    = (const float*)d_in[5];
  const float* b1    = (const float*)d_in[6];
  const float* w2    = (const float*)d_in[7];
  const float* b2    = (const float*)d_in[8];
  float* out = (float*)d_out;

  float* ws  = (float*)d_ws;
  float* ent = ws;                                   // N*H
  float* Bt  = ws + Nn * Hh;                         // N*L*H
  float* Ct  = Bt + (size_t)Nn * Ll * Hh;            // N*L*H  (same ~4.2 MB as round 1)

  k_entagg<<<Nn, 256, 0, stream>>>(wei, wmask, ent);
  k_btct<<<2 * Nn, 256, 0, stream>>>(doc, q, W1, ent, Bt, Ct);
  k_main<<<Nn * Ll, 256, 0, stream>>>(doc, dmask, W1, b1, w2, b2, Bt, Ct, out);
}

// Round 3
// 136.322 us; speedup vs baseline: 3.1671x; 1.0022x over previous
//
#include <hip/hip_runtime.h>
#include <hip/hip_bf16.h>
#include <math.h>

#define Hh 128   // hidden
#define Nn 32    // docs
#define Ll 128   // doc_len
#define W1S 384  // 3H
#define PAD 136  // bf16 elems per LDS row: 272B stride -> 2-way (free) frag reads

typedef __attribute__((ext_vector_type(8))) short short8;
typedef __attribute__((ext_vector_type(4))) float floatx4;

__device__ __forceinline__ unsigned short f2bf(float x) {
  __hip_bfloat16 h = __float2bfloat16(x);
  return __builtin_bit_cast(unsigned short, h);
}
__device__ __forceinline__ float bf2f(short s) {
  unsigned int u = ((unsigned int)(unsigned short)s) << 16;
  return __builtin_bit_cast(float, u);
}
__device__ __forceinline__ short8 pack8(float4 a, float4 b) {
  short8 r;
  r[0] = (short)f2bf(a.x); r[1] = (short)f2bf(a.y);
  r[2] = (short)f2bf(a.z); r[3] = (short)f2bf(a.w);
  r[4] = (short)f2bf(b.x); r[5] = (short)f2bf(b.y);
  r[6] = (short)f2bf(b.z); r[7] = (short)f2bf(b.w);
  return r;
}

// One block per n: ent = mask^T wei; Bt = (doc*ent) @ W1b^T; Ct = (doc*q) @ W1c^T
__launch_bounds__(256, 1)
__global__ void k_prep(const float* __restrict__ wei, const int* __restrict__ wmask,
                       const float* __restrict__ doc, const float* __restrict__ q,
                       const float* __restrict__ W1,
                       float* __restrict__ Bt, float* __restrict__ Ct) {
  __shared__ __align__(16) short docb[Hh * PAD];  // bf16(doc), unscaled
  __shared__ __align__(16) short Wb[Hh * PAD];    // bf16(W1b)
  __shared__ __align__(16) short Wc[Hh * PAD];    // bf16(W1c)
  __shared__ __align__(16) float entL[Hh];
  __shared__ __align__(16) float qL[Hh];
  __shared__ __align__(16) float red[2][Hh];

  int n = blockIdx.x, tid = threadIdx.x;
  const float* docn = doc + (size_t)n * Ll * Hh;
  int e8 = (tid & 15) * 8;  // constant across p since 256 % 16 == 0

  // stage doc / W1b / W1c as bf16
#pragma unroll
  for (int p = 0; p < 8; ++p) {
    int row = p * 16 + (tid >> 4);
    const float4* dp = (const float4*)(docn + (size_t)row * Hh + e8);
    *(short8*)(docb + row * PAD + e8) = pack8(dp[0], dp[1]);
    const float4* wbp = (const float4*)(W1 + (size_t)row * W1S + Hh + e8);
    *(short8*)(Wb + row * PAD + e8) = pack8(wbp[0], wbp[1]);
    const float4* wcp = (const float4*)(W1 + (size_t)row * W1S + 2 * Hh + e8);
    *(short8*)(Wc + row * PAD + e8) = pack8(wcp[0], wcp[1]);
  }
  // ent partial reduce
  {
    int e = tid & 127, half = tid >> 7;
    const float* wp = wei + (size_t)n * Ll * Hh + (size_t)half * 64 * Hh + e;
    const int* mp = wmask + n * Ll + half * 64;
    float a = 0.f;
#pragma unroll 8
    for (int l = 0; l < 64; ++l) a = fmaf((float)mp[l], wp[(size_t)l * Hh], a);
    red[half][e] = a;
  }
  if (tid < Hh) qL[tid] = q[(n >> 3) * Hh + tid];
  __syncthreads();
  if (tid < Hh) entL[tid] = red[0][tid] + red[1][tid];
  __syncthreads();

  int lane = tid & 63, w = tid >> 6;
  int l15 = lane & 15, quad = lane >> 4;

  // per-lane scale fragments and raw doc fragments
  float ef[32], qf[32];
#pragma unroll
  for (int c = 0; c < 4; ++c)
#pragma unroll
    for (int i = 0; i < 8; ++i) {
      int e = c * 32 + quad * 8 + i;
      ef[c * 8 + i] = entL[e];
      qf[c * 8 + i] = qL[e];
    }
  short8 draw[2][4];
#pragma unroll
  for (int mt = 0; mt < 2; ++mt)
#pragma unroll
    for (int c = 0; c < 4; ++c)
      draw[mt][c] = *(const short8*)(docb + (w * 32 + mt * 16 + l15) * PAD + c * 32 + quad * 8);

  for (int which = 0; which < 2; ++which) {
    const short* Ws = which ? Wc : Wb;
    const float* sf = which ? qf : ef;
    floatx4 acc[2][8];
#pragma unroll
    for (int mt = 0; mt < 2; ++mt)
#pragma unroll
      for (int nt = 0; nt < 8; ++nt) acc[mt][nt] = (floatx4){0.f, 0.f, 0.f, 0.f};
#pragma unroll
    for (int c = 0; c < 4; ++c) {
      short8 af[2];
#pragma unroll
      for (int mt = 0; mt < 2; ++mt) {
        float t[8];
#pragma unroll
        for (int i = 0; i < 8; ++i) t[i] = bf2f(draw[mt][c][i]) * sf[c * 8 + i];
        short8 r;
#pragma unroll
        for (int i = 0; i < 8; ++i) r[i] = (short)f2bf(t[i]);
        af[mt] = r;
      }
      short8 bfr[8];
#pragma unroll
      for (int nt = 0; nt < 8; ++nt)
        bfr[nt] = *(const short8*)(Ws + (nt * 16 + l15) * PAD + c * 32 + quad * 8);
#pragma unroll
      for (int mt = 0; mt < 2; ++mt)
#pragma unroll
        for (int nt = 0; nt < 8; ++nt)
          acc[mt][nt] = __builtin_amdgcn_mfma_f32_16x16x32_bf16(af[mt], bfr[nt], acc[mt][nt], 0, 0, 0);
    }
    float* outp = (which ? Ct : Bt) + (size_t)n * Ll * Hh;
#pragma unroll
    for (int mt = 0; mt < 2; ++mt)
#pragma unroll
      for (int nt = 0; nt < 8; ++nt)
#pragma unroll
        for (int r = 0; r < 4; ++r) {
          int k = w * 32 + mt * 16 + quad * 4 + r;
          outp[(size_t)k * Hh + nt * 16 + l15] = acc[mt][nt][r];
        }
  }
}

// One block per (n,j), XCD-swizzled: n = bid & 31 so all j-blocks of n share XCD n%8.
__launch_bounds__(256, 2)
__global__ void k_main(const float* __restrict__ doc, const int* __restrict__ dmask,
                       const float* __restrict__ W1, const float* __restrict__ b1,
                       const float* __restrict__ w2, const float* __restrict__ b2,
                       const float* __restrict__ Bt, const float* __restrict__ Ct,
                       float* __restrict__ out) {
  __shared__ __align__(16) short As[Hh * PAD];  // As[g][e] = bf16(W1a)
  __shared__ __align__(16) short Bs[Hh * PAD];  // Bs[k][e] = bf16(doc*dj)
  __shared__ __align__(16) float sc[Ll];
  __shared__ __align__(16) float scw[Ll];

  int bid = blockIdx.x;
  int n = bid & 31, j = bid >> 5;   // XCD-locality swizzle
  int tid = threadIdx.x;
  const float* docn = doc + (size_t)n * Ll * Hh;
  size_t orow = ((size_t)n * Ll + j) * Hh;

  if (dmask[n * Ll + j] == 0) {     // fully-masked row -> exact zeros (~50% of blocks)
    if (tid < Hh) out[orow + tid] = 0.f;
    return;
  }

  int e8 = (tid & 15) * 8;  // constant across p
  const float4* jp = (const float4*)(docn + (size_t)j * Hh + e8);
  float4 j0 = jp[0], j1 = jp[1];
#pragma unroll
  for (int p = 0; p < 8; ++p) {
    int row = p * 16 + (tid >> 4);
    const float4* wp = (const float4*)(W1 + (size_t)row * W1S + e8);
    *(short8*)(As + row * PAD + e8) = pack8(wp[0], wp[1]);
    const float4* dp = (const float4*)(docn + (size_t)row * Hh + e8);
    float4 d0 = dp[0], d1 = dp[1];
    d0.x *= j0.x; d0.y *= j0.y; d0.z *= j0.z; d0.w *= j0.w;
    d1.x *= j1.x; d1.y *= j1.y; d1.z *= j1.z; d1.w *= j1.w;
    *(short8*)(Bs + row * PAD + e8) = pack8(d0, d1);
  }
  __syncthreads();

  int lane = tid & 63, w = tid >> 6;
  int l15 = lane & 15, quad = lane >> 4;
  floatx4 acc[2][8];
#pragma unroll
  for (int mt = 0; mt < 2; ++mt)
#pragma unroll
    for (int nt = 0; nt < 8; ++nt) acc[mt][nt] = (floatx4){0.f, 0.f, 0.f, 0.f};
#pragma unroll
  for (int e0 = 0; e0 < Hh; e0 += 32) {
    int eo = e0 + quad * 8;
    short8 af[2], bfr[8];
    af[0] = *(const short8*)(Bs + (w * 32 + l15) * PAD + eo);
    af[1] = *(const short8*)(Bs + (w * 32 + 16 + l15) * PAD + eo);
#pragma unroll
    for (int nt = 0; nt < 8; ++nt)
      bfr[nt] = *(const short8*)(As + (nt * 16 + l15) * PAD + eo);
#pragma unroll
    for (int mt = 0; mt < 2; ++mt)
#pragma unroll
      for (int nt = 0; nt < 8; ++nt)
        acc[mt][nt] = __builtin_amdgcn_mfma_f32_16x16x32_bf16(af[mt], bfr[nt], acc[mt][nt], 0, 0, 0);
  }

  // epilogue: tanh(acc + Ct[k,g] + Bt[j,g] + b1[g]) . w2  -> sc[k]
  const float c2 = 2.885390081777927f;  // 2*log2(e)
  float bbc[8], w2r[8];
  const float* btrow = Bt + orow;
#pragma unroll
  for (int nt = 0; nt < 8; ++nt) {
    int g = nt * 16 + l15;
    bbc[nt] = (btrow[g] + b1[g]) * c2;
    w2r[nt] = w2[g];
  }
  const float* ctn = Ct + (size_t)n * Ll * Hh;
#pragma unroll
  for (int mt = 0; mt < 2; ++mt) {
#pragma unroll
    for (int r = 0; r < 4; ++r) {
      int k = w * 32 + mt * 16 + quad * 4 + r;
      const float* ctp = ctn + (size_t)k * Hh + l15;
      float p = 0.f;
#pragma unroll
      for (int nt = 0; nt < 8; ++nt) {
        float s = acc[mt][nt][r] + ctp[nt * 16];
        float a2 = fmaf(s, c2, bbc[nt]);
        float e = exp2f(a2);
        float th = fmaf(-2.f, __builtin_amdgcn_rcpf(e + 1.f), 1.f);
        p = fmaf(th, w2r[nt], p);
      }
      p += __shfl_xor(p, 1);
      p += __shfl_xor(p, 2);
      p += __shfl_xor(p, 4);
      p += __shfl_xor(p, 8);
      if (l15 == 0) sc[k] = p;
    }
  }
  __syncthreads();

  // redundant per-wave masked softmax (no extra barriers)
  {
    float b2v = b2[0];
    const float inv = 0.088388347648318447f;  // 1/sqrt(128)
    const int* dmn = dmask + n * Ll;
    int m0 = dmn[lane], m1 = dmn[lane + 64];
    float s0 = (sc[lane] + b2v) * inv;
    float s1 = (sc[lane + 64] + b2v) * inv;
    s0 = m0 ? s0 : -1e9f;
    s1 = m1 ? s1 : -1e9f;
    float mx = fmaxf(s0, s1);
#pragma unroll
    for (int off = 32; off; off >>= 1) mx = fmaxf(mx, __shfl_xor(mx, off));
    float ex0 = __expf(s0 - mx), ex1 = __expf(s1 - mx);
    float sm = ex0 + ex1;
#pragma unroll
    for (int off = 32; off; off >>= 1) sm += __shfl_xor(sm, off);
    float rden = 1.f / sm;
    scw[lane] = m0 ? ex0 * rden : 0.f;       // all 4 waves write identical values
    scw[lane + 64] = m1 ? ex1 * rden : 0.f;
  }
  __syncthreads();

  // out[j,h] = sum_k w[k] * doc[n,k,h]
  float* ored = (float*)As;  // As dead after GEMM
  int half = tid >> 7, h = tid & 127;
  const float* dbase = docn + (size_t)half * 64 * Hh + h;
  float o = 0.f;
#pragma unroll 8
  for (int kk = 0; kk < 64; ++kk)
    o = fmaf(scw[half * 64 + kk], dbase[(size_t)kk * Hh], o);
  ored[half * Hh + h] = o;
  __syncthreads();
  if (tid < Ll) out[orow + tid] = ored[tid] + ored[Hh + tid];
}

extern "C" void kernel_launch(void* const* d_in, const int* in_sizes, int n_in,
                              void* d_out, int out_size, void* d_ws, size_t ws_size,
                              hipStream_t stream) {
  const float* wei   = (const float*)d_in[0];
  const int*   wmask = (const int*)d_in[1];
  const float* doc   = (const float*)d_in[2];
  const int*   dmask = (const int*)d_in[3];
  const float* q     = (const float*)d_in[4];
  const float* W1    = (const float*)d_in[5];
  const float* b1    = (const float*)d_in[6];
  const float* w2    = (const float*)d_in[7];
  const float* b2    = (const float*)d_in[8];
  float* out = (float*)d_out;

  float* ws = (float*)d_ws;
  float* Bt = ws;                           // N*L*H
  float* Ct = Bt + (size_t)Nn * Ll * Hh;    // N*L*H   (total 4.19 MB, <= round-1 usage)

  k_prep<<<Nn, 256, 0, stream>>>(wei, wmask, doc, q, W1, Bt, Ct);
  k_main<<<Nn * Ll, 256, 0, stream>>>(doc, dmask, W1, b1, w2, b2, Bt, Ct, out);
}